// Round 12
// baseline (328.236 us; speedup 1.0000x reference)
//
#include <hip/hip_runtime.h>
#include <cstdint>

#define BB   128
#define SS   256
#define NDEPTH 655
#define UU   128
#define VV   512   // 4*UU
#define ROWS_PER_BLK 20   // 131 blocks x 20 = 2620 rows of WdWx

typedef _Float16 f16;
typedef _Float16 f16x2 __attribute__((ext_vector_type(2)));

#if __has_builtin(__builtin_amdgcn_fdot2)
#define FDOT2(a, b, c) __builtin_amdgcn_fdot2((a), (b), (c), false)
#else
static __device__ __forceinline__ float FDOT2(f16x2 a, f16x2 b, float c) {
    return c + (float)a.x * (float)b.x + (float)a.y * (float)b.y;
}
#endif

// Raw barrier: LDS-ordering only (R10: neutral vs __syncthreads; strictly weaker).
#define STEP_BARRIER()                                          \
    do {                                                        \
        asm volatile("s_waitcnt lgkmcnt(0)" ::: "memory");      \
        __builtin_amdgcn_s_barrier();                           \
        __builtin_amdgcn_sched_barrier(0);                      \
    } while (0)

// ------ fused: context features + WdWx = W_dense@Wx + base (+seq scalar) ---
__global__ void wdwx_kernel(const float* __restrict__ Wd,      // [2620,128]
                            const float* __restrict__ Wx,      // [128,512]
                            const float* __restrict__ b_dense, // [128]
                            const float* __restrict__ b_lstm,  // [512]
                            const int* __restrict__ last_rule,
                            const int* __restrict__ move_count,
                            const int* __restrict__ node_count,
                            const int* __restrict__ problem_type,
                            float* __restrict__ WdWx,          // [2620,512]
                            float* __restrict__ base,          // [512]
                            float* __restrict__ out, int write_seq) {
    const int v  = threadIdx.x;          // 0..511
    const int k0 = blockIdx.x * ROWS_PER_BLK;

    // context features (first 9 blocks cover BB*35 = 4480 elements)
    int gid = blockIdx.x * 512 + v;
    if (gid < BB * 35) {
        int b = gid / 35, cc = gid % 35;
        float val;
        if (cc == 0)      val = (float)last_rule[b];
        else if (cc == 1) val = (float)move_count[b];
        else if (cc == 2) val = (float)node_count[b];
        else              val = (problem_type[b] == (cc - 3)) ? 1.0f : 0.0f;
        out[gid] = val;
    }
    if (write_seq && gid == 0)
        out[(size_t)BB*35 + (size_t)BB*UU + (size_t)BB*SS*UU] = (float)SS;

    float acc[ROWS_PER_BLK] = {};        // static-indexed (rule #20)
    for (int uu = 0; uu < UU; ++uu) {
        float wx = Wx[uu * VV + v];      // coalesced; Wx reread 131x (was 655x)
        #pragma unroll
        for (int r = 0; r < ROWS_PER_BLK; ++r)
            acc[r] = fmaf(Wd[(size_t)(k0 + r) * UU + uu], wx, acc[r]);
    }
    #pragma unroll
    for (int r = 0; r < ROWS_PER_BLK; ++r)
        WdWx[(size_t)(k0 + r) * VV + v] = acc[r];

    if (blockIdx.x == 0) {
        float a = 0.f;
        for (int uu = 0; uu < UU; ++uu) a = fmaf(b_dense[uu], Wx[uu * VV + v], a);
        base[v] = a + b_lstm[v];
    }
}

// ---------------- persistent per-batch LSTM, quad split-K, f16 dot --------
// R11 structure (best: 210us) + DISTANCE-2 gather prefetch: the WdWx gathers
// are h-independent; with only 1-step distance the L3/HBM latency (~600-900+
// cyc; WdWx 5.37MB > 4MB XCD L2) is exposed at each step top = the ~1300cyc
// idle floor invariant across R8/R11. Loop unrolled x2 with NAMED register
// sets gA*/gB* (rule #20: no runtime-indexed reg arrays).
__global__ __launch_bounds__(512, 2)
void lstm_kernel(const int* __restrict__ bwd,  const int* __restrict__ fwd,
                 const int* __restrict__ lbwd, const int* __restrict__ lfwd,
                 const float* __restrict__ WdWx,   // [2620,512]
                 const float* __restrict__ base,   // [512]
                 const float* __restrict__ Wh,     // [128,512]
                 float* __restrict__ hidden_states, // [B,S,U]
                 float* __restrict__ lstm_vectors) {// [B,U]
    const int b    = blockIdx.x;
    const int t    = threadIdx.x;     // 0..511
    const int lane = t & 63;
    const int w    = t >> 6;          // wave 0..7
    const int q    = lane & 3;        // gate lane (keras i,f,g,o)
    const int u    = w * 16 + (lane >> 2);   // unit 0..127
    const int col  = q * UU + u;             // this thread's gate column

    __shared__ __align__(16) unsigned char h2buf[2][320]; // 4 chunks x 80B
    __shared__ int idx_lds[SS][4];

    // wh2[j*4+g] = (Wh[32q+2j][g*128+u], Wh[32q+2j+1][g*128+u]) — FULL static
    // unroll (rule #20: runtime index -> scratch, R5: 8x slowdown)
    f16x2 wh2[64];
    #pragma unroll
    for (int j = 0; j < 16; ++j) {
        #pragma unroll
        for (int g = 0; g < 4; ++g) {
            float w0 = Wh[(size_t)(32*q + 2*j    ) * VV + g*UU + u];
            float w1 = Wh[(size_t)(32*q + 2*j + 1) * VV + g*UU + u];
            f16x2 pk; pk.x = (f16)w0; pk.y = (f16)w1;
            wh2[j*4 + g] = pk;
        }
    }

    for (int s = t; s < SS; s += 512) {
        idx_lds[s][0] =            bwd [b*SS + s];
        idx_lds[s][1] =   NDEPTH + fwd [b*SS + s];
        idx_lds[s][2] = 2*NDEPTH + lbwd[b*SS + s];
        idx_lds[s][3] = 3*NDEPTH + lfwd[b*SS + s];
    }
    if (t < UU)
        ((f16*)(h2buf[0] + 80*(t >> 5)))[t & 31] = (f16)0.0f;
    float c      = 0.0f;               // cell state, replicated per quad (f32)
    float bias   = base[col];
    float h_last = 0.0f;
    __syncthreads();

    // prologue: prefetch gathers for steps 0 (gA) and 1 (gB)
    float gA0 = WdWx[(size_t)idx_lds[0][0] * VV + col];
    float gA1 = WdWx[(size_t)idx_lds[0][1] * VV + col];
    float gA2 = WdWx[(size_t)idx_lds[0][2] * VV + col];
    float gA3 = WdWx[(size_t)idx_lds[0][3] * VV + col];
    float gB0 = WdWx[(size_t)idx_lds[1][0] * VV + col];
    float gB1 = WdWx[(size_t)idx_lds[1][1] * VV + col];
    float gB2 = WdWx[(size_t)idx_lds[1][2] * VV + col];
    float gB3 = WdWx[(size_t)idx_lds[1][3] * VV + col];

    const bool b0 = (q & 1) != 0;
    const bool b1 = (q & 2) != 0;

    int p = 0;

#define DOTW(word, j)                                            \
    do {                                                         \
        f16x2 hv = __builtin_bit_cast(f16x2, (word));            \
        pp0 = FDOT2(hv, wh2[(j)*4+0], pp0);                      \
        pp1 = FDOT2(hv, wh2[(j)*4+1], pp1);                      \
        pp2 = FDOT2(hv, wh2[(j)*4+2], pp2);                      \
        pp3 = FDOT2(hv, wh2[(j)*4+3], pp3);                      \
    } while (0)

#define LSTM_STEP(G0, G1, G2, G3, SCUR)                                   \
    {                                                                     \
        float z = bias + ((G0) + (G1)) + ((G2) + (G3));                   \
        if ((SCUR) + 2 < SS) {   /* distance-2 prefetch, h-independent */ \
            G0 = WdWx[(size_t)idx_lds[(SCUR)+2][0] * VV + col];           \
            G1 = WdWx[(size_t)idx_lds[(SCUR)+2][1] * VV + col];           \
            G2 = WdWx[(size_t)idx_lds[(SCUR)+2][2] * VV + col];           \
            G3 = WdWx[(size_t)idx_lds[(SCUR)+2][3] * VV + col];           \
        }                                                                 \
        const uint4* hb = (const uint4*)(h2buf[p] + 80 * q);              \
        uint4 A = hb[0], Bv = hb[1], Cv = hb[2], Dv = hb[3];              \
        float pp0 = 0.f, pp1 = 0.f, pp2 = 0.f, pp3 = 0.f;                 \
        DOTW(A.x,  0); DOTW(A.y,  1); DOTW(A.z,  2); DOTW(A.w,  3);       \
        DOTW(Bv.x, 4); DOTW(Bv.y, 5); DOTW(Bv.z, 6); DOTW(Bv.w, 7);       \
        DOTW(Cv.x, 8); DOTW(Cv.y, 9); DOTW(Cv.z,10); DOTW(Cv.w,11);       \
        DOTW(Dv.x,12); DOTW(Dv.y,13); DOTW(Dv.z,14); DOTW(Dv.w,15);      \
        /* quad transpose-reduce (R8-validated) */                        \
        float keepA = b0 ? pp1 : pp0;                                     \
        float keepB = b0 ? pp3 : pp2;                                     \
        float sendA = b0 ? pp0 : pp1;                                     \
        float sendB = b0 ? pp2 : pp3;                                     \
        float sA = keepA + __shfl_xor(sendA, 1);                          \
        float sB = keepB + __shfl_xor(sendB, 1);                          \
        float send2 = b1 ? sA : sB;                                       \
        z += (b1 ? sB : sA) + __shfl_xor(send2, 2);                       \
        /* activation: sigmoid; gate 2 (g) = tanh via 2*sigm(2z)-1 */     \
        float xs = (q == 2) ? 2.0f * z : z;                               \
        float sg = __fdividef(1.0f, 1.0f + __expf(-xs));                  \
        float a  = (q == 2) ? 2.0f * sg - 1.0f : sg;                      \
        /* quad exchange (R5/R6-validated gate algebra) */                \
        float v1 = __shfl_xor(a, 1);                                      \
        float v2 = __shfl_xor(a, 2);                                      \
        float v3 = __shfl_xor(v1, 2);                                     \
        float ig = (q & 1) ? v1 * v3 : a * v2;                            \
        float gf = (q & 1) ? ((q & 2) ? v2 : a)                           \
                           : ((q & 2) ? v3 : v1);                         \
        float go = (q & 1) ? ((q & 2) ? a  : v2)                          \
                           : ((q & 2) ? v1 : v3);                         \
        c = fmaf(gf, c, ig);                                              \
        float e  = __expf(2.0f * c);                                      \
        float tc = 1.0f - __fdividef(2.0f, e + 1.0f);                     \
        float h  = go * tc;                                               \
        if (q == 0) {                                                     \
            ((f16*)(h2buf[p ^ 1] + 80*(u >> 5)))[u & 31] = (f16)h;        \
            hidden_states[((size_t)b * SS + (SCUR)) * UU + u] = h;        \
            h_last = h;                                                   \
        }                                                                 \
        STEP_BARRIER();                                                   \
        p ^= 1;                                                           \
    }

    for (int s = 0; s < SS; s += 2) {
        LSTM_STEP(gA0, gA1, gA2, gA3, s)
        LSTM_STEP(gB0, gB1, gB2, gB3, s + 1)
    }
#undef LSTM_STEP
#undef DOTW

    if (q == 0) lstm_vectors[(size_t)b * UU + u] = h_last;
}

// ---------------------------------------------------------------------------
extern "C" void kernel_launch(void* const* d_in, const int* in_sizes, int n_in,
                              void* d_out, int out_size, void* d_ws, size_t ws_size,
                              hipStream_t stream) {
    const int* move_count   = (const int*)d_in[0];
    // d_in[1] moves_remaining: unused by the reference
    const int* last_rule    = (const int*)d_in[2];
    const int* node_count   = (const int*)d_in[3];
    const int* problem_type = (const int*)d_in[4];
    const int* bwd          = (const int*)d_in[5];
    const int* fwd          = (const int*)d_in[6];
    const int* lbwd         = (const int*)d_in[7];
    const int* lfwd         = (const int*)d_in[8];
    const float* Wd         = (const float*)d_in[9];
    const float* b_dense    = (const float*)d_in[10];
    const float* Wx         = (const float*)d_in[11];
    const float* Wh         = (const float*)d_in[12];
    const float* b_lstm     = (const float*)d_in[13];

    float* out  = (float*)d_out;
    float* WdWx = (float*)d_ws;                        // 2620*512*4 = 5.37 MB
    float* base = WdWx + (size_t)(4 * NDEPTH) * VV;    // +512 floats

    float* lstm_out = out + BB * 35;
    float* hs_out   = lstm_out + BB * UU;
    int write_seq = (out_size > BB*35 + BB*UU + BB*SS*UU) ? 1 : 0;

    wdwx_kernel<<<131, VV, 0, stream>>>(Wd, Wx, b_dense, b_lstm,
                                        last_rule, move_count, node_count,
                                        problem_type, WdWx, base, out, write_seq);
    lstm_kernel<<<BB, 512, 0, stream>>>(bwd, fwd, lbwd, lfwd, WdWx, base, Wh,
                                        hs_out, lstm_out);
}

// Round 13
// 294.945 us; speedup vs baseline: 1.1129x; 1.1129x over previous
//
#include <hip/hip_runtime.h>
#include <cstdint>

#define BB   128
#define SS   256
#define NDEPTH 655
#define UU   128
#define VV   512   // 4*UU
#define ROWS_PER_BLK 20   // 131 blocks x 20 = 2620 rows of WdWx

typedef _Float16 f16;
typedef _Float16 f16x2 __attribute__((ext_vector_type(2)));

#if __has_builtin(__builtin_amdgcn_fdot2)
#define FDOT2(a, b, c) __builtin_amdgcn_fdot2((a), (b), (c), false)
#else
static __device__ __forceinline__ float FDOT2(f16x2 a, f16x2 b, float c) {
    return c + (float)a.x * (float)b.x + (float)a.y * (float)b.y;
}
#endif

// Quad shuffles via DPP quad_perm: 1-2 cyc VALU operand modifier, vs
// __shfl_xor's ds_bpermute (LDS pipe, ~100cyc). Our 6 shuffles/step are all
// within a quad (gate group = lane&3) and sit on the loop-carried serial
// chain — R8..R12's invariant ~1300 idle cyc/step.
__device__ __forceinline__ float qswap1(float x) {   // lane ^ 1
    return __builtin_bit_cast(float,
        __builtin_amdgcn_mov_dpp(__builtin_bit_cast(int, x), 0xB1, 0xF, 0xF, true));
}
__device__ __forceinline__ float qswap2(float x) {   // lane ^ 2
    return __builtin_bit_cast(float,
        __builtin_amdgcn_mov_dpp(__builtin_bit_cast(int, x), 0x4E, 0xF, 0xF, true));
}

// Raw barrier: LDS-ordering only (R10: neutral vs __syncthreads; strictly weaker).
#define STEP_BARRIER()                                          \
    do {                                                        \
        asm volatile("s_waitcnt lgkmcnt(0)" ::: "memory");      \
        __builtin_amdgcn_s_barrier();                           \
        __builtin_amdgcn_sched_barrier(0);                      \
    } while (0)

// ------ fused: context features + WdWx = W_dense@Wx + base (+seq scalar) ---
__global__ void wdwx_kernel(const float* __restrict__ Wd,      // [2620,128]
                            const float* __restrict__ Wx,      // [128,512]
                            const float* __restrict__ b_dense, // [128]
                            const float* __restrict__ b_lstm,  // [512]
                            const int* __restrict__ last_rule,
                            const int* __restrict__ move_count,
                            const int* __restrict__ node_count,
                            const int* __restrict__ problem_type,
                            float* __restrict__ WdWx,          // [2620,512]
                            float* __restrict__ base,          // [512]
                            float* __restrict__ out, int write_seq) {
    const int v  = threadIdx.x;          // 0..511
    const int k0 = blockIdx.x * ROWS_PER_BLK;

    // context features (first 9 blocks cover BB*35 = 4480 elements)
    int gid = blockIdx.x * 512 + v;
    if (gid < BB * 35) {
        int b = gid / 35, cc = gid % 35;
        float val;
        if (cc == 0)      val = (float)last_rule[b];
        else if (cc == 1) val = (float)move_count[b];
        else if (cc == 2) val = (float)node_count[b];
        else              val = (problem_type[b] == (cc - 3)) ? 1.0f : 0.0f;
        out[gid] = val;
    }
    if (write_seq && gid == 0)
        out[(size_t)BB*35 + (size_t)BB*UU + (size_t)BB*SS*UU] = (float)SS;

    float acc[ROWS_PER_BLK] = {};        // static-indexed (rule #20)
    for (int uu = 0; uu < UU; ++uu) {
        float wx = Wx[uu * VV + v];      // coalesced; Wx reread 131x (was 655x)
        #pragma unroll
        for (int r = 0; r < ROWS_PER_BLK; ++r)
            acc[r] = fmaf(Wd[(size_t)(k0 + r) * UU + uu], wx, acc[r]);
    }
    #pragma unroll
    for (int r = 0; r < ROWS_PER_BLK; ++r)
        WdWx[(size_t)(k0 + r) * VV + v] = acc[r];

    if (blockIdx.x == 0) {
        float a = 0.f;
        for (int uu = 0; uu < UU; ++uu) a = fmaf(b_dense[uu], Wx[uu * VV + v], a);
        base[v] = a + b_lstm[v];
    }
}

// ---------------- persistent per-batch LSTM, quad split-K, f16 dot, DPP ---
// R11 structure (best: 210us), distance-1 gather prefetch (R12's distance-2
// regressed), all 6 per-step quad shuffles as DPP quad_perm.
__global__ __launch_bounds__(512, 2)
void lstm_kernel(const int* __restrict__ bwd,  const int* __restrict__ fwd,
                 const int* __restrict__ lbwd, const int* __restrict__ lfwd,
                 const float* __restrict__ WdWx,   // [2620,512]
                 const float* __restrict__ base,   // [512]
                 const float* __restrict__ Wh,     // [128,512]
                 float* __restrict__ hidden_states, // [B,S,U]
                 float* __restrict__ lstm_vectors) {// [B,U]
    const int b    = blockIdx.x;
    const int t    = threadIdx.x;     // 0..511
    const int lane = t & 63;
    const int w    = t >> 6;          // wave 0..7
    const int q    = lane & 3;        // gate lane (keras i,f,g,o)
    const int u    = w * 16 + (lane >> 2);   // unit 0..127
    const int col  = q * UU + u;             // this thread's gate column

    __shared__ __align__(16) unsigned char h2buf[2][320]; // 4 chunks x 80B
    __shared__ int idx_lds[SS][4];

    // wh2[j*4+g] = (Wh[32q+2j][g*128+u], Wh[32q+2j+1][g*128+u]) — FULL static
    // unroll (rule #20: runtime index -> scratch, R5: 8x slowdown)
    f16x2 wh2[64];
    #pragma unroll
    for (int j = 0; j < 16; ++j) {
        #pragma unroll
        for (int g = 0; g < 4; ++g) {
            float w0 = Wh[(size_t)(32*q + 2*j    ) * VV + g*UU + u];
            float w1 = Wh[(size_t)(32*q + 2*j + 1) * VV + g*UU + u];
            f16x2 pk; pk.x = (f16)w0; pk.y = (f16)w1;
            wh2[j*4 + g] = pk;
        }
    }

    for (int s = t; s < SS; s += 512) {
        idx_lds[s][0] =            bwd [b*SS + s];
        idx_lds[s][1] =   NDEPTH + fwd [b*SS + s];
        idx_lds[s][2] = 2*NDEPTH + lbwd[b*SS + s];
        idx_lds[s][3] = 3*NDEPTH + lfwd[b*SS + s];
    }
    if (t < UU)
        ((f16*)(h2buf[0] + 80*(t >> 5)))[t & 31] = (f16)0.0f;
    float c      = 0.0f;               // cell state, replicated per quad (f32)
    float bias   = base[col];
    float h_last = 0.0f;
    __syncthreads();

    // prefetch step-0 gather (f32 rows of WdWx)
    float g0 = WdWx[(size_t)idx_lds[0][0] * VV + col];
    float g1 = WdWx[(size_t)idx_lds[0][1] * VV + col];
    float g2 = WdWx[(size_t)idx_lds[0][2] * VV + col];
    float g3 = WdWx[(size_t)idx_lds[0][3] * VV + col];

    const bool b0 = (q & 1) != 0;
    const bool b1 = (q & 2) != 0;

    int p = 0;
    for (int s = 0; s < SS; ++s) {
        float z = bias + (g0 + g1) + (g2 + g3);
        if (s + 1 < SS) {              // prefetch next step under the dot
            g0 = WdWx[(size_t)idx_lds[s+1][0] * VV + col];
            g1 = WdWx[(size_t)idx_lds[s+1][1] * VV + col];
            g2 = WdWx[(size_t)idx_lds[s+1][2] * VV + col];
            g3 = WdWx[(size_t)idx_lds[s+1][3] * VV + col];
        }

        // partial dots over my 32-h chunk (f16) for all 4 gates of unit u
        const uint4* hb = (const uint4*)(h2buf[p] + 80 * q);
        uint4 A = hb[0], Bv = hb[1], Cv = hb[2], Dv = hb[3];
        float pp0 = 0.f, pp1 = 0.f, pp2 = 0.f, pp3 = 0.f;
        #define DOTW(word, j)                                            \
            do {                                                         \
                f16x2 hv = __builtin_bit_cast(f16x2, (word));            \
                pp0 = FDOT2(hv, wh2[(j)*4+0], pp0);                      \
                pp1 = FDOT2(hv, wh2[(j)*4+1], pp1);                      \
                pp2 = FDOT2(hv, wh2[(j)*4+2], pp2);                      \
                pp3 = FDOT2(hv, wh2[(j)*4+3], pp3);                      \
            } while (0)
        DOTW(A.x,  0); DOTW(A.y,  1); DOTW(A.z,  2); DOTW(A.w,  3);
        DOTW(Bv.x, 4); DOTW(Bv.y, 5); DOTW(Bv.z, 6); DOTW(Bv.w, 7);
        DOTW(Cv.x, 8); DOTW(Cv.y, 9); DOTW(Cv.z,10); DOTW(Cv.w,11);
        DOTW(Dv.x,12); DOTW(Dv.y,13); DOTW(Dv.z,14); DOTW(Dv.w,15);
        #undef DOTW

        // quad transpose-reduce (R8-validated algebra, DPP movement)
        float keepA = b0 ? pp1 : pp0;
        float keepB = b0 ? pp3 : pp2;
        float sendA = b0 ? pp0 : pp1;
        float sendB = b0 ? pp2 : pp3;
        float sA = keepA + qswap1(sendA);
        float sB = keepB + qswap1(sendB);
        float send2 = b1 ? sA : sB;
        z += (b1 ? sB : sA) + qswap2(send2);

        // activation: sigmoid; gate 2 (g) = tanh via 2*sigm(2z)-1
        float xs = (q == 2) ? 2.0f * z : z;
        float sg = __fdividef(1.0f, 1.0f + __expf(-xs));
        float a  = (q == 2) ? 2.0f * sg - 1.0f : sg;

        // quad exchange (R5/R6-validated gate algebra, DPP movement)
        float v1 = qswap1(a);
        float v2 = qswap2(a);
        float v3 = qswap2(v1);
        float ig = (q & 1) ? v1 * v3 : a * v2;                    // i*g
        float gf = (q & 1) ? ((q & 2) ? v2 : a)
                           : ((q & 2) ? v3 : v1);                 // f
        float go = (q & 1) ? ((q & 2) ? a  : v2)
                           : ((q & 2) ? v1 : v3);                 // o
        c = fmaf(gf, c, ig);
        float e  = __expf(2.0f * c);
        float tc = 1.0f - __fdividef(2.0f, e + 1.0f);             // tanh(c)
        float h  = go * tc;

        if (q == 0) {
            ((f16*)(h2buf[p ^ 1] + 80*(u >> 5)))[u & 31] = (f16)h; // dot copy
            hidden_states[((size_t)b * SS + s) * UU + u] = h;      // exact f32
            h_last = h;
        }
        STEP_BARRIER();
        p ^= 1;
    }
    if (q == 0) lstm_vectors[(size_t)b * UU + u] = h_last;
}

// ---------------------------------------------------------------------------
extern "C" void kernel_launch(void* const* d_in, const int* in_sizes, int n_in,
                              void* d_out, int out_size, void* d_ws, size_t ws_size,
                              hipStream_t stream) {
    const int* move_count   = (const int*)d_in[0];
    // d_in[1] moves_remaining: unused by the reference
    const int* last_rule    = (const int*)d_in[2];
    const int* node_count   = (const int*)d_in[3];
    const int* problem_type = (const int*)d_in[4];
    const int* bwd          = (const int*)d_in[5];
    const int* fwd          = (const int*)d_in[6];
    const int* lbwd         = (const int*)d_in[7];
    const int* lfwd         = (const int*)d_in[8];
    const float* Wd         = (const float*)d_in[9];
    const float* b_dense    = (const float*)d_in[10];
    const float* Wx         = (const float*)d_in[11];
    const float* Wh         = (const float*)d_in[12];
    const float* b_lstm     = (const float*)d_in[13];

    float* out  = (float*)d_out;
    float* WdWx = (float*)d_ws;                        // 2620*512*4 = 5.37 MB
    float* base = WdWx + (size_t)(4 * NDEPTH) * VV;    // +512 floats

    float* lstm_out = out + BB * 35;
    float* hs_out   = lstm_out + BB * UU;
    int write_seq = (out_size > BB*35 + BB*UU + BB*SS*UU) ? 1 : 0;

    wdwx_kernel<<<131, VV, 0, stream>>>(Wd, Wx, b_dense, b_lstm,
                                        last_rule, move_count, node_count,
                                        problem_type, WdWx, base, out, write_seq);
    lstm_kernel<<<BB, 512, 0, stream>>>(bwd, fwd, lbwd, lfwd, WdWx, base, Wh,
                                        hs_out, lstm_out);
}